// Round 3
// baseline (108.953 us; speedup 1.0000x reference)
//
#include <hip/hip_runtime.h>
#include <cstdint>

typedef unsigned short ushort_t;
typedef __attribute__((ext_vector_type(4))) float f32x4;
typedef __attribute__((ext_vector_type(8))) __bf16 bf16x8;
typedef __attribute__((ext_vector_type(8))) unsigned short ushort8;

#define NB 16384
#define DIN 512
#define DH 512
#define DK 1024   // IN + H

// f32 -> bf16 bits, round-to-nearest-even (values are all normal floats here)
__device__ __forceinline__ unsigned short f2b(float f) {
    unsigned u = __builtin_bit_cast(unsigned, f);
    unsigned r = u + 0x7fffu + ((u >> 16) & 1u);
    return (unsigned short)(r >> 16);
}

// async global->LDS, 16B per lane. LDS dest must be wave-uniform base + lane*16
// (our per-thread lds addresses are exactly t*16-contiguous per wave).
__device__ __forceinline__ void gll16(const void* g, void* lds) {
    __builtin_amdgcn_global_load_lds(
        (__attribute__((address_space(1))) unsigned int*)(uintptr_t)g,
        (__attribute__((address_space(3))) unsigned int*)(unsigned int)(uintptr_t)lds,
        16, 0, 0);
}

// ---------------- prep kernels ----------------

// 8 f32 -> 8 bf16 per thread; grid sized exactly (count % 2048 == 0)
__global__ __launch_bounds__(256) void k_f32_to_bf16(const float* __restrict__ s,
                                                     ushort_t* __restrict__ d) {
    size_t g = (size_t)blockIdx.x * 256 + threadIdx.x;
    const float* p = s + g * 8;
    f32x4 f0 = *(const f32x4*)p;
    f32x4 f1 = *(const f32x4*)(p + 4);
    ushort8 o;
#pragma unroll
    for (int j = 0; j < 4; ++j) { o[j] = f2b(f0[j]); o[j + 4] = f2b(f1[j]); }
    *(ushort8*)(d + g * 8) = o;
}

// W [1024][ncols] f32 (row-major, [k][n]) -> Wt [ncols][1024] bf16 ([n][k])
__global__ __launch_bounds__(256) void k_transpose_w(const float* __restrict__ W,
                                                     ushort_t* __restrict__ Wt, int ncols) {
    __shared__ float tile[32][33];
    int n0 = blockIdx.x * 32, k0 = blockIdx.y * 32;
    int tx = threadIdx.x, ty = threadIdx.y;  // blockDim (32,8)
#pragma unroll
    for (int i = 0; i < 32; i += 8)
        tile[ty + i][tx] = W[(size_t)(k0 + ty + i) * ncols + n0 + tx];
    __syncthreads();
#pragma unroll
    for (int i = 0; i < 32; i += 8)
        Wt[(size_t)(n0 + ty + i) * DK + k0 + tx] = f2b(tile[tx][ty + i]);
}

// ---------------- GEMM 1: lin = [x,h] @ W_in, fused gate epilogue ----------------
// A: XB [16384][512] + HB [16384][512] (bf16, k<512 from XB, else HB)
// B: WT [1024][1024] bf16 = W_in^T ([n][k])
// block computes rows m0..m0+127, learn cols n0..n0+127 AND forget cols n0+512..
__global__ __launch_bounds__(256, 2) void k_gemm1(
    const ushort_t* __restrict__ XB, const ushort_t* __restrict__ HB,
    const ushort_t* __restrict__ WT, const float* __restrict__ b_in,
    const float* __restrict__ h, float* __restrict__ hnew, ushort_t* __restrict__ HN) {
    __shared__ ushort_t As[128 * 32];
    __shared__ ushort_t BsL[128 * 32];
    __shared__ ushort_t BsF[128 * 32];

    const int t = threadIdx.x;
    const int lane = t & 63;
    const int wave = t >> 6;
    const int wm = wave >> 1, wn = wave & 1;  // 2x2 waves over 128x128
    const int m0 = blockIdx.x * 128;
    const int n0 = blockIdx.y * 128;  // in [0,512)

    f32x4 accL[4][4] = {};
    f32x4 accF[4][4] = {};

    const int srow = t >> 2;        // staging row 0..63
    const int skel = (t & 3) * 8;   // staging k-elem offset
    const size_t arow = (size_t)(m0 + srow) * 512;
    const ushort_t* gBL = WT + (size_t)(n0 + srow) * DK + skel;
    const ushort_t* gBF = WT + (size_t)(n0 + 512 + srow) * DK + skel;
    ushort_t* lA = As + t * 8;
    ushort_t* lBL = BsL + t * 8;
    ushort_t* lBF = BsF + t * 8;

    for (int kt = 0; kt < DK; kt += 32) {
        const ushort_t* abase =
            (kt < 512) ? (XB + arow + kt + skel) : (HB + arow + (kt - 512) + skel);
        __syncthreads();  // prior compute done before overwrite
        gll16(abase, lA);
        gll16(abase + 64 * 512, lA + 64 * 32);
        gll16(gBL + kt, lBL);
        gll16(gBL + kt + 64 * DK, lBL + 64 * 32);
        gll16(gBF + kt, lBF);
        gll16(gBF + kt + 64 * DK, lBF + 64 * 32);
        asm volatile("s_waitcnt vmcnt(0)" ::: "memory");
        __syncthreads();

        const int fr = lane & 15;
        const int kq = (lane >> 4) * 8;
        bf16x8 av[4], blv[4], bfv[4];
#pragma unroll
        for (int i = 0; i < 4; ++i) {
            av[i] = *(const bf16x8*)(As + (wm * 64 + i * 16 + fr) * 32 + kq);
            blv[i] = *(const bf16x8*)(BsL + (wn * 64 + i * 16 + fr) * 32 + kq);
            bfv[i] = *(const bf16x8*)(BsF + (wn * 64 + i * 16 + fr) * 32 + kq);
        }
#pragma unroll
        for (int i = 0; i < 4; ++i)
#pragma unroll
            for (int j = 0; j < 4; ++j) {
                accL[i][j] = __builtin_amdgcn_mfma_f32_16x16x32_bf16(av[i], blv[j], accL[i][j], 0, 0, 0);
                accF[i][j] = __builtin_amdgcn_mfma_f32_16x16x32_bf16(av[i], bfv[j], accF[i][j], 0, 0, 0);
            }
    }

    // epilogue: C/D map col=lane&15, row=(lane>>4)*4+reg  [m89/m91 verified]
    const int fr = lane & 15;
    const int fq = lane >> 4;
#pragma unroll
    for (int i = 0; i < 4; ++i)
#pragma unroll
        for (int j = 0; j < 4; ++j) {
            const int c = n0 + wn * 64 + j * 16 + fr;
#pragma unroll
            for (int r = 0; r < 4; ++r) {
                const int row = m0 + wm * 64 + i * 16 + fq * 4 + r;
                float lp = accL[i][j][r] + b_in[c];
                float fp = accF[i][j][r] + b_in[c + 512];
                float hv = h[(size_t)row * 512 + c];
                float fm = 1.0f / (1.0f + expf(-fp));
                float lr = tanhf(lp);
                float hn = fm * hv + (1.0f - fm) * lr;
                hnew[(size_t)row * 512 + c] = hn;
                HN[(size_t)row * 512 + c] = f2b(hn);
            }
        }
}

// ---------------- GEMM 2: out = tanh([x,h_new] @ W_out + b_out) ----------------
__global__ __launch_bounds__(256, 2) void k_gemm2(
    const ushort_t* __restrict__ XB, const ushort_t* __restrict__ HN,
    const ushort_t* __restrict__ WT, const float* __restrict__ b_out,
    float* __restrict__ out) {
    __shared__ ushort_t As[128 * 32];
    __shared__ ushort_t Bs[128 * 32];

    const int t = threadIdx.x;
    const int lane = t & 63;
    const int wave = t >> 6;
    const int wm = wave >> 1, wn = wave & 1;
    const int m0 = blockIdx.x * 128;
    const int n0 = blockIdx.y * 128;  // in [0,512)

    f32x4 acc[4][4] = {};

    const int srow = t >> 2;
    const int skel = (t & 3) * 8;
    const size_t arow = (size_t)(m0 + srow) * 512;
    const ushort_t* gB = WT + (size_t)(n0 + srow) * DK + skel;
    ushort_t* lA = As + t * 8;
    ushort_t* lB = Bs + t * 8;

    for (int kt = 0; kt < DK; kt += 32) {
        const ushort_t* abase =
            (kt < 512) ? (XB + arow + kt + skel) : (HN + arow + (kt - 512) + skel);
        __syncthreads();
        gll16(abase, lA);
        gll16(abase + 64 * 512, lA + 64 * 32);
        gll16(gB + kt, lB);
        gll16(gB + kt + 64 * DK, lB + 64 * 32);
        asm volatile("s_waitcnt vmcnt(0)" ::: "memory");
        __syncthreads();

        const int fr = lane & 15;
        const int kq = (lane >> 4) * 8;
        bf16x8 av[4], bv[4];
#pragma unroll
        for (int i = 0; i < 4; ++i) {
            av[i] = *(const bf16x8*)(As + (wm * 64 + i * 16 + fr) * 32 + kq);
            bv[i] = *(const bf16x8*)(Bs + (wn * 64 + i * 16 + fr) * 32 + kq);
        }
#pragma unroll
        for (int i = 0; i < 4; ++i)
#pragma unroll
            for (int j = 0; j < 4; ++j)
                acc[i][j] = __builtin_amdgcn_mfma_f32_16x16x32_bf16(av[i], bv[j], acc[i][j], 0, 0, 0);
    }

    const int fr = lane & 15;
    const int fq = lane >> 4;
#pragma unroll
    for (int i = 0; i < 4; ++i)
#pragma unroll
        for (int j = 0; j < 4; ++j) {
            const int c = n0 + wn * 64 + j * 16 + fr;
#pragma unroll
            for (int r = 0; r < 4; ++r) {
                const int row = m0 + wm * 64 + i * 16 + fq * 4 + r;
                out[(size_t)row * 512 + c] = tanhf(acc[i][j][r] + b_out[c]);
            }
        }
}

extern "C" void kernel_launch(void* const* d_in, const int* in_sizes, int n_in,
                              void* d_out, int out_size, void* d_ws, size_t ws_size,
                              hipStream_t stream) {
    const float* x = (const float*)d_in[0];
    const float* h = (const float*)d_in[1];
    const float* W_in = (const float*)d_in[2];
    const float* b_in = (const float*)d_in[3];
    const float* W_out = (const float*)d_in[4];
    const float* b_out = (const float*)d_in[5];

    float* out = (float*)d_out;                    // [16384][512]
    float* hnew = out + (size_t)NB * DH;           // [16384][512]

    // workspace: XB, HB, HN (bf16 16MB each), WTI (2MB), WTO (1MB) = ~51.5MB
    ushort_t* XB = (ushort_t*)d_ws;
    ushort_t* HB = XB + (size_t)NB * 512;
    ushort_t* HN = HB + (size_t)NB * 512;
    ushort_t* WTI = HN + (size_t)NB * 512;
    ushort_t* WTO = WTI + (size_t)1024 * 1024;

    k_f32_to_bf16<<<4096, 256, 0, stream>>>(x, XB);
    k_f32_to_bf16<<<4096, 256, 0, stream>>>(h, HB);
    k_transpose_w<<<dim3(32, 32), dim3(32, 8), 0, stream>>>(W_in, WTI, 1024);
    k_transpose_w<<<dim3(16, 32), dim3(32, 8), 0, stream>>>(W_out, WTO, 512);
    k_gemm1<<<dim3(128, 4), 256, 0, stream>>>(XB, HB, WTI, b_in, h, hnew, HN);
    k_gemm2<<<dim3(128, 4), 256, 0, stream>>>(XB, HN, WTO, b_out, out);
}

// Round 4
// 93.752 us; speedup vs baseline: 1.1621x; 1.1621x over previous
//
#include <hip/hip_runtime.h>
#include <cstdint>

typedef unsigned short ushort_t;
typedef __attribute__((ext_vector_type(4))) float f32x4;
typedef __attribute__((ext_vector_type(8))) __bf16 bf16x8;
typedef __attribute__((ext_vector_type(8))) unsigned short ushort8;

#define NB 16384
#define DK 1024   // IN + H

// f32 -> bf16 bits, round-to-nearest-even
__device__ __forceinline__ unsigned short f2b(float f) {
    unsigned u = __builtin_bit_cast(unsigned, f);
    unsigned r = u + 0x7fffu + ((u >> 16) & 1u);
    return (unsigned short)(r >> 16);
}
__device__ __forceinline__ float b2f(ushort_t b) {
    unsigned u = ((unsigned)b) << 16;
    return __builtin_bit_cast(float, u);
}
// fast sigmoid / tanh via v_exp_f32 (+ fast divide); abs err ~1e-6
__device__ __forceinline__ float fast_sigmoid(float x) {
    return __fdividef(1.0f, 1.0f + __expf(-x));
}
__device__ __forceinline__ float fast_tanh(float x) {
    return __fdividef(2.0f, 1.0f + __expf(-2.0f * x)) - 1.0f;
}

// async global->LDS, 16B per lane (LDS dest = wave-uniform base + lane*16)
__device__ __forceinline__ void gll16(const void* g, void* lds) {
    __builtin_amdgcn_global_load_lds(
        (__attribute__((address_space(1))) unsigned int*)(uintptr_t)g,
        (__attribute__((address_space(3))) unsigned int*)(unsigned int)(uintptr_t)lds,
        16, 0, 0);
}

// ---------------- prep kernels ----------------

__global__ __launch_bounds__(256) void k_f32_to_bf16(const float* __restrict__ s,
                                                     ushort_t* __restrict__ d) {
    size_t g = (size_t)blockIdx.x * 256 + threadIdx.x;
    const float* p = s + g * 8;
    f32x4 f0 = *(const f32x4*)p;
    f32x4 f1 = *(const f32x4*)(p + 4);
    ushort8 o;
#pragma unroll
    for (int j = 0; j < 4; ++j) { o[j] = f2b(f0[j]); o[j + 4] = f2b(f1[j]); }
    *(ushort8*)(d + g * 8) = o;
}

// W [1024][ncols] f32 ([k][n]) -> Wt [ncols][1024] bf16 ([n][k])
__global__ __launch_bounds__(256) void k_transpose_w(const float* __restrict__ W,
                                                     ushort_t* __restrict__ Wt, int ncols) {
    __shared__ float tile[32][33];
    int n0 = blockIdx.x * 32, k0 = blockIdx.y * 32;
    int tx = threadIdx.x, ty = threadIdx.y;  // blockDim (32,8)
#pragma unroll
    for (int i = 0; i < 32; i += 8)
        tile[ty + i][tx] = W[(size_t)(k0 + ty + i) * ncols + n0 + tx];
    __syncthreads();
#pragma unroll
    for (int i = 0; i < 32; i += 8)
        Wt[(size_t)(n0 + ty + i) * DK + k0 + tx] = f2b(tile[tx][ty + i]);
}

// ---------------- GEMM 1: lin = [x,h] @ W_in, fused gate epilogue ----------------
// 2-phase double-buffered: stage(t+1) issued before compute(t); ONE barrier/iter.
__global__ __launch_bounds__(256, 2) void k_gemm1(
    const ushort_t* __restrict__ XB, const ushort_t* __restrict__ HB,
    const ushort_t* __restrict__ WT, const float* __restrict__ b_in,
    float* __restrict__ hnew, ushort_t* __restrict__ HN) {
    __shared__ ushort_t As[2][128 * 32];
    __shared__ ushort_t BsL[2][128 * 32];
    __shared__ ushort_t BsF[2][128 * 32];

    const int t = threadIdx.x;
    const int lane = t & 63;
    const int wave = t >> 6;
    const int wm = wave >> 1, wn = wave & 1;  // 2x2 waves over 128x128
    const int m0 = blockIdx.x * 128;
    const int n0 = blockIdx.y * 128;  // in [0,512)

    f32x4 accL[4][4] = {};
    f32x4 accF[4][4] = {};

    const int srow = t >> 2;        // staging row 0..63
    const int skel = (t & 3) * 8;   // staging k-elem offset
    const size_t arow = (size_t)(m0 + srow) * 512;
    const ushort_t* gBL = WT + (size_t)(n0 + srow) * DK + skel;
    const ushort_t* gBF = WT + (size_t)(n0 + 512 + srow) * DK + skel;

    auto stage = [&](int it, int buf) {
        const int kt = it * 32;
        const ushort_t* abase =
            (kt < 512) ? (XB + arow + kt + skel) : (HB + arow + (kt - 512) + skel);
        ushort_t* a = &As[buf][t * 8];
        ushort_t* bl = &BsL[buf][t * 8];
        ushort_t* bf = &BsF[buf][t * 8];
        gll16(abase, a);
        gll16(abase + 64 * 512, a + 64 * 32);
        gll16(gBL + kt, bl);
        gll16(gBL + kt + 64 * DK, bl + 64 * 32);
        gll16(gBF + kt, bf);
        gll16(gBF + kt + 64 * DK, bf + 64 * 32);
    };

    const int fr = lane & 15;
    const int kq = (lane >> 4) * 8;

    stage(0, 0);
    int cur = 0;
    for (int it = 0; it < 32; ++it) {
        asm volatile("s_waitcnt vmcnt(0)" ::: "memory");
        __syncthreads();
        if (it + 1 < 32) stage(it + 1, cur ^ 1);

        bf16x8 av[4], blv[4], bfv[4];
#pragma unroll
        for (int i = 0; i < 4; ++i) {
            av[i]  = *(const bf16x8*)(&As[cur][(wm * 64 + i * 16 + fr) * 32 + kq]);
            blv[i] = *(const bf16x8*)(&BsL[cur][(wn * 64 + i * 16 + fr) * 32 + kq]);
            bfv[i] = *(const bf16x8*)(&BsF[cur][(wn * 64 + i * 16 + fr) * 32 + kq]);
        }
#pragma unroll
        for (int i = 0; i < 4; ++i)
#pragma unroll
            for (int j = 0; j < 4; ++j) {
                accL[i][j] = __builtin_amdgcn_mfma_f32_16x16x32_bf16(av[i], blv[j], accL[i][j], 0, 0, 0);
                accF[i][j] = __builtin_amdgcn_mfma_f32_16x16x32_bf16(av[i], bfv[j], accF[i][j], 0, 0, 0);
            }
        cur ^= 1;
    }

    // epilogue: C/D map col=lane&15, row=(lane>>4)*4+reg
    const int fq = lane >> 4;
    float bl4[4], bf4[4];
#pragma unroll
    for (int j = 0; j < 4; ++j) {
        const int c = n0 + wn * 64 + j * 16 + fr;
        bl4[j] = b_in[c];
        bf4[j] = b_in[c + 512];
    }
#pragma unroll
    for (int i = 0; i < 4; ++i)
#pragma unroll
        for (int j = 0; j < 4; ++j) {
            const int c = n0 + wn * 64 + j * 16 + fr;
#pragma unroll
            for (int r = 0; r < 4; ++r) {
                const int row = m0 + wm * 64 + i * 16 + fq * 4 + r;
                float lp = accL[i][j][r] + bl4[j];
                float fp = accF[i][j][r] + bf4[j];
                float hv = b2f(HB[(size_t)row * 512 + c]);
                float fm = fast_sigmoid(fp);
                float lr = fast_tanh(lp);
                float hn = fm * hv + (1.0f - fm) * lr;
                hnew[(size_t)row * 512 + c] = hn;
                HN[(size_t)row * 512 + c] = f2b(hn);
            }
        }
}

// ---------------- GEMM 2: out = tanh([x,h_new] @ W_out + b_out) ----------------
__global__ __launch_bounds__(256, 2) void k_gemm2(
    const ushort_t* __restrict__ XB, const ushort_t* __restrict__ HN,
    const ushort_t* __restrict__ WT, const float* __restrict__ b_out,
    float* __restrict__ out) {
    __shared__ ushort_t As[2][128 * 32];
    __shared__ ushort_t Bs[2][128 * 32];

    const int t = threadIdx.x;
    const int lane = t & 63;
    const int wave = t >> 6;
    const int wm = wave >> 1, wn = wave & 1;
    const int m0 = blockIdx.x * 128;
    const int n0 = blockIdx.y * 128;

    f32x4 acc[4][4] = {};

    const int srow = t >> 2;
    const int skel = (t & 3) * 8;
    const size_t arow = (size_t)(m0 + srow) * 512;
    const ushort_t* gB = WT + (size_t)(n0 + srow) * DK + skel;

    auto stage = [&](int it, int buf) {
        const int kt = it * 32;
        const ushort_t* abase =
            (kt < 512) ? (XB + arow + kt + skel) : (HN + arow + (kt - 512) + skel);
        ushort_t* a = &As[buf][t * 8];
        ushort_t* b = &Bs[buf][t * 8];
        gll16(abase, a);
        gll16(abase + 64 * 512, a + 64 * 32);
        gll16(gB + kt, b);
        gll16(gB + kt + 64 * DK, b + 64 * 32);
    };

    const int fr = lane & 15;
    const int kq = (lane >> 4) * 8;

    stage(0, 0);
    int cur = 0;
    for (int it = 0; it < 32; ++it) {
        asm volatile("s_waitcnt vmcnt(0)" ::: "memory");
        __syncthreads();
        if (it + 1 < 32) stage(it + 1, cur ^ 1);

        bf16x8 av[4], bv[4];
#pragma unroll
        for (int i = 0; i < 4; ++i) {
            av[i] = *(const bf16x8*)(&As[cur][(wm * 64 + i * 16 + fr) * 32 + kq]);
            bv[i] = *(const bf16x8*)(&Bs[cur][(wn * 64 + i * 16 + fr) * 32 + kq]);
        }
#pragma unroll
        for (int i = 0; i < 4; ++i)
#pragma unroll
            for (int j = 0; j < 4; ++j)
                acc[i][j] = __builtin_amdgcn_mfma_f32_16x16x32_bf16(av[i], bv[j], acc[i][j], 0, 0, 0);
        cur ^= 1;
    }

    const int fq = lane >> 4;
#pragma unroll
    for (int i = 0; i < 4; ++i)
#pragma unroll
        for (int j = 0; j < 4; ++j) {
            const int c = n0 + wn * 64 + j * 16 + fr;
#pragma unroll
            for (int r = 0; r < 4; ++r) {
                const int row = m0 + wm * 64 + i * 16 + fq * 4 + r;
                out[(size_t)row * 512 + c] = fast_tanh(acc[i][j][r] + b_out[c]);
            }
        }
}

extern "C" void kernel_launch(void* const* d_in, const int* in_sizes, int n_in,
                              void* d_out, int out_size, void* d_ws, size_t ws_size,
                              hipStream_t stream) {
    const float* x = (const float*)d_in[0];
    const float* h = (const float*)d_in[1];
    const float* W_in = (const float*)d_in[2];
    const float* b_in = (const float*)d_in[3];
    const float* W_out = (const float*)d_in[4];
    const float* b_out = (const float*)d_in[5];

    float* out = (float*)d_out;                    // [16384][512]
    float* hnew = out + (size_t)NB * 512;          // [16384][512]

    ushort_t* XB = (ushort_t*)d_ws;
    ushort_t* HB = XB + (size_t)NB * 512;
    ushort_t* HN = HB + (size_t)NB * 512;
    ushort_t* WTI = HN + (size_t)NB * 512;
    ushort_t* WTO = WTI + (size_t)1024 * 1024;

    k_f32_to_bf16<<<4096, 256, 0, stream>>>(x, XB);
    k_f32_to_bf16<<<4096, 256, 0, stream>>>(h, HB);
    k_transpose_w<<<dim3(32, 32), dim3(32, 8), 0, stream>>>(W_in, WTI, 1024);
    k_transpose_w<<<dim3(16, 32), dim3(32, 8), 0, stream>>>(W_out, WTO, 512);
    k_gemm1<<<dim3(128, 4), 256, 0, stream>>>(XB, HB, WTI, b_in, hnew, HN);
    k_gemm2<<<dim3(128, 4), 256, 0, stream>>>(XB, HN, WTO, b_out, out);
}